// Round 2
// baseline (5195.115 us; speedup 1.0000x reference)
//
#include <hip/hip_runtime.h>
#include <math.h>

// Problem constants
#define B_  32
#define T_  577
#define D_  768
#define BT  18464            // B_*T_
#define H3  2304             // 3*D_
#define HD  3072             // 4*D_
#define NH  12
#define DH  64
#define TT  332929ull        // T_*T_
#define LNEPS 1e-6f

// ---------------- LayerNorm ----------------
__global__ __launch_bounds__(256) void ln_kernel(const float* __restrict__ x,
    const float* __restrict__ w, const float* __restrict__ b,
    float* __restrict__ y) {
  int row = blockIdx.x;
  const float* xr = x + (size_t)row * D_;
  int t = threadIdx.x;
  float v0 = xr[t], v1 = xr[t + 256], v2 = xr[t + 512];
  float s  = v0 + v1 + v2;
  float ss = v0*v0 + v1*v1 + v2*v2;
  #pragma unroll
  for (int o = 32; o >= 1; o >>= 1) {
    s  += __shfl_xor(s,  o, 64);
    ss += __shfl_xor(ss, o, 64);
  }
  __shared__ float rs_[4], rss_[4];
  int wid = t >> 6;
  if ((t & 63) == 0) { rs_[wid] = s; rss_[wid] = ss; }
  __syncthreads();
  s  = rs_[0]  + rs_[1]  + rs_[2]  + rs_[3];
  ss = rss_[0] + rss_[1] + rss_[2] + rss_[3];
  float mu  = s * (1.0f / D_);
  float var = ss * (1.0f / D_) - mu * mu;
  float rstd = rsqrtf(var + LNEPS);
  float* yr = y + (size_t)row * D_;
  yr[t]       = (v0 - mu) * rstd * w[t]       + b[t];
  yr[t + 256] = (v1 - mu) * rstd * w[t + 256] + b[t + 256];
  yr[t + 512] = (v2 - mu) * rstd * w[t + 512] + b[t + 512];
}

// ---------------- Big GEMM: C = epi(A[M,K](lda) @ W[K,N] + bias) ----------------
// Requires K%16==0, N%128==0, lda%4==0. M guarded. EPI: 0=bias, 1=bias+res, 2=bias+gelu
template <int EPI>
__global__ __launch_bounds__(256) void gemm128(const float* __restrict__ A, int lda,
    const float* __restrict__ W, const float* __restrict__ bias,
    const float* __restrict__ res, float* __restrict__ C,
    int M, int N, int K) {
  __shared__ float As[16][132];
  __shared__ float Bs[16][132];
  int tid = threadIdx.x;
  int m_base = blockIdx.y * 128, n_base = blockIdx.x * 128;
  int ty = tid >> 4, tx = tid & 15;
  int m0 = ty * 8, n0 = tx * 8;
  float acc[8][8] = {};
  for (int kc = 0; kc < K; kc += 16) {
    #pragma unroll
    for (int l = 0; l < 2; ++l) {
      int f = tid * 2 + l;
      int row = f >> 2, k4 = (f & 3) * 4;
      int gm = m_base + row;
      float4 v = make_float4(0.f, 0.f, 0.f, 0.f);
      if (gm < M) v = *(const float4*)(A + (size_t)gm * lda + kc + k4);
      As[k4 + 0][row] = v.x; As[k4 + 1][row] = v.y;
      As[k4 + 2][row] = v.z; As[k4 + 3][row] = v.w;
    }
    #pragma unroll
    for (int l = 0; l < 2; ++l) {
      int f = tid * 2 + l;
      int kr = f >> 5, n4 = (f & 31) * 4;
      float4 v = *(const float4*)(W + (size_t)(kc + kr) * N + n_base + n4);
      *(float4*)&Bs[kr][n4] = v;
    }
    __syncthreads();
    #pragma unroll
    for (int kk = 0; kk < 16; ++kk) {
      float a[8], bb[8];
      *(float4*)&a[0] = *(const float4*)&As[kk][m0];
      *(float4*)&a[4] = *(const float4*)&As[kk][m0 + 4];
      *(float4*)&bb[0] = *(const float4*)&Bs[kk][n0];
      *(float4*)&bb[4] = *(const float4*)&Bs[kk][n0 + 4];
      #pragma unroll
      for (int i = 0; i < 8; ++i)
        #pragma unroll
        for (int j = 0; j < 8; ++j)
          acc[i][j] += a[i] * bb[j];
    }
    __syncthreads();
  }
  #pragma unroll
  for (int i = 0; i < 8; ++i) {
    int gm = m_base + m0 + i;
    if (gm < M) {
      float* crow = C + (size_t)gm * N + n_base + n0;
      const float* rrow = res ? (res + (size_t)gm * N + n_base + n0) : nullptr;
      #pragma unroll
      for (int j = 0; j < 8; ++j) {
        float v = acc[i][j] + bias[n_base + n0 + j];
        if (EPI == 1) v += rrow[j];
        if (EPI == 2) v = 0.5f * v * (1.0f + erff(v * 0.70710678118654752f));
        crow[j] = v;
      }
    }
  }
}

// ---------------- Attention: dp = scale * Q @ K^T (per chunk-batch bb, head h) ----------------
__global__ __launch_bounds__(256) void attn_qk(const float* __restrict__ qkvc,
    float* __restrict__ dp) {
  int z = blockIdx.z;
  int bb = z / NH, h = z % NH;
  const float* Qp = qkvc + (size_t)bb * T_ * H3 + (size_t)h * DH;
  const float* Kp = Qp + D_;
  float* Cp = dp + (size_t)z * TT;
  int qbase = blockIdx.y * 64, kbase = blockIdx.x * 64;
  __shared__ float Qs[16][68], Ks[16][68];
  int tid = threadIdx.x;
  int ty = tid >> 4, tx = tid & 15;
  int m0 = ty * 4, n0 = tx * 4;
  float acc[4][4] = {};
  for (int kc = 0; kc < DH; kc += 16) {
    int r = tid >> 2, k4 = (tid & 3) * 4;
    {
      int gq = qbase + r;
      float4 v = make_float4(0.f, 0.f, 0.f, 0.f);
      if (gq < T_) v = *(const float4*)(Qp + (size_t)gq * H3 + kc + k4);
      Qs[k4 + 0][r] = v.x; Qs[k4 + 1][r] = v.y;
      Qs[k4 + 2][r] = v.z; Qs[k4 + 3][r] = v.w;
    }
    {
      int gk = kbase + r;
      float4 v = make_float4(0.f, 0.f, 0.f, 0.f);
      if (gk < T_) v = *(const float4*)(Kp + (size_t)gk * H3 + kc + k4);
      Ks[k4 + 0][r] = v.x; Ks[k4 + 1][r] = v.y;
      Ks[k4 + 2][r] = v.z; Ks[k4 + 3][r] = v.w;
    }
    __syncthreads();
    #pragma unroll
    for (int kk = 0; kk < 16; ++kk) {
      float a[4], bv[4];
      *(float4*)a  = *(const float4*)&Qs[kk][m0];
      *(float4*)bv = *(const float4*)&Ks[kk][n0];
      #pragma unroll
      for (int i = 0; i < 4; ++i)
        #pragma unroll
        for (int j = 0; j < 4; ++j)
          acc[i][j] += a[i] * bv[j];
    }
    __syncthreads();
  }
  #pragma unroll
  for (int i = 0; i < 4; ++i) {
    int gq = qbase + m0 + i;
    if (gq < T_) {
      #pragma unroll
      for (int j = 0; j < 4; ++j) {
        int gk = kbase + n0 + j;
        if (gk < T_) Cp[(size_t)gq * T_ + gk] = acc[i][j] * 0.125f;
      }
    }
  }
}

// ---------------- softmax over the HEADS axis ----------------
__global__ __launch_bounds__(256) void softmax_h(float* __restrict__ dp) {
  size_t qk = (size_t)blockIdx.x * 256 + threadIdx.x;
  if (qk >= TT) return;
  float* base = dp + (size_t)blockIdx.y * NH * TT + qk;
  float v[NH];
  float m = -1e30f;
  #pragma unroll
  for (int h = 0; h < NH; ++h) { v[h] = base[(size_t)h * TT]; m = fmaxf(m, v[h]); }
  float s = 0.f;
  #pragma unroll
  for (int h = 0; h < NH; ++h) { v[h] = expf(v[h] - m); s += v[h]; }
  float inv = 1.0f / s;
  #pragma unroll
  for (int h = 0; h < NH; ++h) base[(size_t)h * TT] = v[h] * inv;
}

// ---------------- Attention: wa = attn @ V, written into dead Q slot of qkv ----------------
__global__ __launch_bounds__(256) void attn_av(float* __restrict__ qkvc,
    const float* __restrict__ dp) {
  int z = blockIdx.z;
  int bb = z / NH, h = z % NH;
  const float* Ap = dp + (size_t)z * TT;
  const float* Vp = qkvc + (size_t)bb * T_ * H3 + 2 * D_ + (size_t)h * DH;
  float* Cp = qkvc + (size_t)bb * T_ * H3 + (size_t)h * DH;  // Q slot (dead)
  int qbase = blockIdx.y * 64;
  __shared__ float As[16][68], Bs[16][68];
  int tid = threadIdx.x;
  int ty = tid >> 4, tx = tid & 15;
  int m0 = ty * 4, n0 = tx * 4;
  float acc[4][4] = {};
  for (int kc = 0; kc < T_; kc += 16) {
    {
      int r = tid >> 2, k4 = (tid & 3) * 4;
      int gq = qbase + r;
      #pragma unroll
      for (int i = 0; i < 4; ++i) {
        int gk = kc + k4 + i;
        As[k4 + i][r] = (gq < T_ && gk < T_) ? Ap[(size_t)gq * T_ + gk] : 0.0f;
      }
    }
    {
      int kr = tid >> 4, n4 = (tid & 15) * 4;
      int gk = kc + kr;
      float4 v = make_float4(0.f, 0.f, 0.f, 0.f);
      if (gk < T_) v = *(const float4*)(Vp + (size_t)gk * H3 + n4);
      *(float4*)&Bs[kr][n4] = v;
    }
    __syncthreads();
    #pragma unroll
    for (int kk = 0; kk < 16; ++kk) {
      float a[4], bv[4];
      *(float4*)a  = *(const float4*)&As[kk][m0];
      *(float4*)bv = *(const float4*)&Bs[kk][n0];
      #pragma unroll
      for (int i = 0; i < 4; ++i)
        #pragma unroll
        for (int j = 0; j < 4; ++j)
          acc[i][j] += a[i] * bv[j];
    }
    __syncthreads();
  }
  #pragma unroll
  for (int i = 0; i < 4; ++i) {
    int gq = qbase + m0 + i;
    if (gq < T_) {
      float4 v = make_float4(acc[i][0], acc[i][1], acc[i][2], acc[i][3]);
      *(float4*)(Cp + (size_t)gq * H3 + n0) = v;
    }
  }
}

// ---------------- launch ----------------
extern "C" void kernel_launch(void* const* d_in, const int* in_sizes, int n_in,
                              void* d_out, int out_size, void* d_ws, size_t ws_size,
                              hipStream_t stream) {
  const float* x     = (const float*)d_in[0];
  const float* ln1w  = (const float*)d_in[1];
  const float* ln1b  = (const float*)d_in[2];
  const float* qkvw  = (const float*)d_in[3];
  const float* qkvb  = (const float*)d_in[4];
  const float* projw = (const float*)d_in[5];
  const float* projb = (const float*)d_in[6];
  const float* ln2w  = (const float*)d_in[7];
  const float* ln2b  = (const float*)d_in[8];
  const float* fc1w  = (const float*)d_in[9];
  const float* fc1b  = (const float*)d_in[10];
  const float* fc2w  = (const float*)d_in[11];
  const float* fc2b  = (const float*)d_in[12];
  float* out = (float*)d_out;   // doubles as x2 (residual after attention)
  float* ws  = (float*)d_ws;

  size_t ws_floats = ws_size / 4;

  // ---- attention branch, chunked over batches to fit ws ----
  // per batch: y T*D + qkv T*3D + dp NH*T*T
  const size_t per_batch = (size_t)T_ * D_ + (size_t)T_ * H3 + (size_t)NH * TT;
  int NB = (int)(ws_floats / per_batch);
  if (NB < 1)  NB = 1;
  if (NB > B_) NB = B_;

  for (int b0 = 0; b0 < B_; b0 += NB) {
    int nb = (B_ - b0 < NB) ? (B_ - b0) : NB;
    int rows = nb * T_;
    float* y    = ws;
    float* qkvc = ws + (size_t)NB * T_ * D_;
    float* dp   = qkvc + (size_t)NB * T_ * H3;
    const float* xc = x + (size_t)b0 * T_ * D_;
    float* outc = out + (size_t)b0 * T_ * D_;

    ln_kernel<<<rows, 256, 0, stream>>>(xc, ln1w, ln1b, y);
    gemm128<0><<<dim3(H3 / 128, (rows + 127) / 128), 256, 0, stream>>>(
        y, D_, qkvw, qkvb, nullptr, qkvc, rows, H3, D_);
    attn_qk<<<dim3(10, 10, nb * NH), 256, 0, stream>>>(qkvc, dp);
    softmax_h<<<dim3((unsigned)((TT + 255) / 256), nb), 256, 0, stream>>>(dp);
    attn_av<<<dim3(1, 10, nb * NH), 256, 0, stream>>>(qkvc, dp);
    // proj: A = wa living in Q slots of qkvc (lda = 3D); out = x + wa@W
    gemm128<1><<<dim3(D_ / 128, (rows + 127) / 128), 256, 0, stream>>>(
        qkvc, H3, projw, projb, xc, outc, rows, D_, D_);
  }

  // ---- MLP branch, chunked over rows to fit ws ----
  // per row: y D + hdn 4D
  size_t ch = ws_floats / (size_t)(D_ + HD);
  int CH = (int)((ch > (size_t)BT) ? BT : ch);
  CH &= ~127;
  if (CH < 128) CH = 128;

  for (int r0 = 0; r0 < BT; r0 += CH) {
    int rows = (BT - r0 < CH) ? (BT - r0) : CH;
    float* y2  = ws;
    float* hdn = ws + (size_t)CH * D_;
    float* oc  = out + (size_t)r0 * D_;

    ln_kernel<<<rows, 256, 0, stream>>>(oc, ln2w, ln2b, y2);
    gemm128<2><<<dim3(HD / 128, (rows + 127) / 128), 256, 0, stream>>>(
        y2, D_, fc1w, fc1b, nullptr, hdn, rows, HD, D_);
    gemm128<1><<<dim3(D_ / 128, (rows + 127) / 128), 256, 0, stream>>>(
        hdn, HD, fc2w, fc2b, oc, oc, rows, D_, HD);
  }
}

// Round 3
// 1467.104 us; speedup vs baseline: 3.5411x; 3.5411x over previous
//
#include <hip/hip_runtime.h>
#include <math.h>

typedef unsigned short u16;
typedef __attribute__((ext_vector_type(8))) short bf8;      // 8 bf16 MFMA operand (4 VGPR)
typedef __attribute__((ext_vector_type(8))) unsigned short us8;
typedef __attribute__((ext_vector_type(4))) float f4;

#define B_  32
#define T_  577
#define D_  768
#define BT  18464
#define H3  2304
#define HD  3072
#define NH  12
#define DH  64
#define TT  332929ull        // T_*T_
#define TP  608              // T_ padded to mult of 32 (K dim of AV)
#define LNEPS 1e-6f

__device__ __forceinline__ u16 f2bf(float f) {
  unsigned int u = __float_as_uint(f);
  u += 0x7fffu + ((u >> 16) & 1u);       // round-to-nearest-even
  return (u16)(u >> 16);
}

// ---------------- LayerNorm fp32 -> bf16 ----------------
__global__ __launch_bounds__(256) void ln_bf16(const float* __restrict__ x,
    const float* __restrict__ w, const float* __restrict__ b, u16* __restrict__ y) {
  int row = blockIdx.x;
  const float* xr = x + (size_t)row * D_;
  int t = threadIdx.x;
  float v0 = xr[t], v1 = xr[t + 256], v2 = xr[t + 512];
  float s  = v0 + v1 + v2;
  float ss = v0*v0 + v1*v1 + v2*v2;
  #pragma unroll
  for (int o = 32; o >= 1; o >>= 1) {
    s  += __shfl_xor(s,  o, 64);
    ss += __shfl_xor(ss, o, 64);
  }
  __shared__ float rs_[4], rss_[4];
  int wid = t >> 6;
  if ((t & 63) == 0) { rs_[wid] = s; rss_[wid] = ss; }
  __syncthreads();
  s  = rs_[0]  + rs_[1]  + rs_[2]  + rs_[3];
  ss = rss_[0] + rss_[1] + rss_[2] + rss_[3];
  float mu  = s * (1.0f / D_);
  float var = ss * (1.0f / D_) - mu * mu;
  float rstd = rsqrtf(var + LNEPS);
  u16* yr = y + (size_t)row * D_;
  yr[t]       = f2bf((v0 - mu) * rstd * w[t]       + b[t]);
  yr[t + 256] = f2bf((v1 - mu) * rstd * w[t + 256] + b[t + 256]);
  yr[t + 512] = f2bf((v2 - mu) * rstd * w[t + 512] + b[t + 512]);
}

// ---------------- weight fp32 [K,N] -> bf16 transposed [N,K] ----------------
// grid: x = N/64, y = K/64 (both multiples of 64)
__global__ __launch_bounds__(256) void wconv(const float* __restrict__ W,
    u16* __restrict__ Wt, int K, int N) {
  __shared__ float tile[64][68];
  int n0 = blockIdx.x * 64, k0 = blockIdx.y * 64;
  int t = threadIdx.x;
  #pragma unroll
  for (int r = 0; r < 4; ++r) {
    int flat = r * 256 + t;
    int kr = flat >> 4, g = flat & 15;
    float4 v = *(const float4*)(W + (size_t)(k0 + kr) * N + n0 + g * 4);
    *(float4*)&tile[kr][g * 4] = v;
  }
  __syncthreads();
  #pragma unroll
  for (int r = 0; r < 2; ++r) {
    int flat = r * 256 + t;
    int n = flat >> 3, g2 = flat & 7;
    us8 o;
    #pragma unroll
    for (int j = 0; j < 8; ++j) o[j] = f2bf(tile[g2 * 8 + j][n]);
    *(us8*)(Wt + (size_t)(n0 + n) * K + k0 + g2 * 8) = o;
  }
}

// ---------------- build Vt [z][128][TP] from qkvbf V-slot ----------------
// grid: x = 10 (k-tiles of 64), y = 2 (y=1 zero-fills rows 64..127), z = nb*NH
__global__ __launch_bounds__(256) void vt_prep(const u16* __restrict__ qkvbf,
    u16* __restrict__ Vt) {
  int z = blockIdx.z;
  int bb = z / NH, h = z - bb * NH;
  u16* out = Vt + (size_t)z * 128 * TP;
  int k0 = blockIdx.x * 64;
  int t = threadIdx.x;
  if (blockIdx.y == 1) {
    #pragma unroll
    for (int r = 0; r < 2; ++r) {
      int flat = r * 256 + t;
      int n = 64 + (flat >> 3), g = flat & 7;
      int kc = k0 + g * 8;
      if (kc < TP) {
        us8 zz = {0,0,0,0,0,0,0,0};
        *(us8*)(out + (size_t)n * TP + kc) = zz;
      }
    }
    return;
  }
  __shared__ u16 tile[64][72];
  const u16* src = qkvbf + ((size_t)bb * T_) * H3 + 2 * D_ + h * DH;
  #pragma unroll
  for (int r = 0; r < 2; ++r) {
    int flat = r * 256 + t;
    int kr = flat >> 3, g = flat & 7;
    int gk = k0 + kr;
    us8 v = {0,0,0,0,0,0,0,0};
    if (gk < T_) v = *(const us8*)(src + (size_t)gk * H3 + g * 8);
    *(us8*)&tile[kr][g * 8] = v;
  }
  __syncthreads();
  #pragma unroll
  for (int r = 0; r < 2; ++r) {
    int flat = r * 256 + t;
    int n = flat >> 3, g2 = flat & 7;
    int kc = k0 + g2 * 8;
    if (kc < TP) {
      us8 o;
      #pragma unroll
      for (int j = 0; j < 8; ++j) o[j] = tile[g2 * 8 + j][n];
      *(us8*)(out + (size_t)n * TP + kc) = o;
    }
  }
}

// ---------------- softmax over heads; fp32 dp -> bf16 P (padded to TP) ----------------
__global__ __launch_bounds__(256) void softmax_pad(const float* __restrict__ dp,
    u16* __restrict__ P) {
  int bb = blockIdx.y;
  int i = blockIdx.x * 256 + threadIdx.x;
  if (i >= T_ * TP) return;
  int qq = i / TP, kp = i - qq * TP;
  u16* Pb = P + (size_t)bb * NH * T_ * TP + (size_t)qq * TP + kp;
  if (kp >= T_) {
    #pragma unroll
    for (int h = 0; h < NH; ++h) Pb[(size_t)h * T_ * TP] = 0;
    return;
  }
  const float* db = dp + (size_t)bb * NH * TT + (size_t)qq * T_ + kp;
  float v[NH];
  float m = -1e30f;
  #pragma unroll
  for (int h = 0; h < NH; ++h) { v[h] = db[(size_t)h * TT]; m = fmaxf(m, v[h]); }
  float s = 0.f;
  #pragma unroll
  for (int h = 0; h < NH; ++h) { v[h] = expf(v[h] - m); s += v[h]; }
  float inv = 1.0f / s;
  #pragma unroll
  for (int h = 0; h < NH; ++h) Pb[(size_t)h * T_ * TP] = f2bf(v[h] * inv);
}

// ---------------- bf16 MFMA GEMM: C = epi(A[M,K] @ Bt[N,K]^T) ----------------
// 128x128 tile, BK=32, 16x16x32 MFMA, 4 waves each 64x64.
// EPI: 0 = bias -> bf16 C        1 = bias+res -> f32 C
//      2 = bias+gelu -> bf16 C   3 = *scale -> f32 C      4 = plain -> bf16 C
// bmode: 0 plain; 1 QK^T (A=Q slot, Bt=K slot of qkvbf, C=dp);
//        2 AV    (A=P, Bt=Vt, C=Q slot of qkvbf)
template <int EPI>
__global__ __launch_bounds__(256) void gemm_bf16(
    const u16* __restrict__ Abase, int lda,
    const u16* __restrict__ Bbase, int ldb,
    const float* __restrict__ bias,
    const float* __restrict__ res, int ldr,
    float* __restrict__ Cf, u16* __restrict__ Cb, int ldc,
    int M, int Nst, int Nb, int K, float scale, int bmode) {
  __shared__ u16 As[128 * 32];
  __shared__ u16 Bs[128 * 32];
  int z = blockIdx.z;
  size_t aoff = 0, boff = 0, coff = 0;
  if (bmode == 1) {
    int bb = z / NH, h = z - bb * NH;
    aoff = (size_t)bb * T_ * H3 + (size_t)h * DH;
    boff = aoff + D_;
    coff = (size_t)z * TT;
  } else if (bmode == 2) {
    int bb = z / NH, h = z - bb * NH;
    aoff = (size_t)z * T_ * TP;
    boff = (size_t)z * 128 * TP;
    coff = (size_t)bb * T_ * H3 + (size_t)h * DH;
  }
  const u16* A  = Abase + aoff;
  const u16* Bt = Bbase + boff;

  int tid = threadIdx.x;
  int m_base = blockIdx.y * 128, n_base = blockIdx.x * 128;
  int wid = tid >> 6, lane = tid & 63;
  int wm = (wid >> 1) * 64, wn = (wid & 1) * 64;
  int lm = lane & 15, q = lane >> 4;
  int srow = tid >> 2, sg = tid & 3;

  f4 acc[4][4] = {};

  for (int kc = 0; kc < K; kc += 32) {
    bf8 va[2], vb[2];
    #pragma unroll
    for (int r = 0; r < 2; ++r) {
      int row = r * 64 + srow;
      int gm = m_base + row; gm = gm < M ? gm : M - 1;
      va[r] = *(const bf8*)(A + (size_t)gm * lda + kc + sg * 8);
      int gn = n_base + row; gn = gn < Nb ? gn : Nb - 1;
      vb[r] = *(const bf8*)(Bt + (size_t)gn * ldb + kc + sg * 8);
    }
    __syncthreads();
    #pragma unroll
    for (int r = 0; r < 2; ++r) {
      int row = r * 64 + srow;
      *(bf8*)&As[row * 32 + sg * 8] = va[r];
      *(bf8*)&Bs[row * 32 + sg * 8] = vb[r];
    }
    __syncthreads();
    bf8 af[4], bfr[4];
    #pragma unroll
    for (int mt = 0; mt < 4; ++mt)
      af[mt] = *(const bf8*)&As[(wm + mt * 16 + lm) * 32 + q * 8];
    #pragma unroll
    for (int nt = 0; nt < 4; ++nt)
      bfr[nt] = *(const bf8*)&Bs[(wn + nt * 16 + lm) * 32 + q * 8];
    #pragma unroll
    for (int mt = 0; mt < 4; ++mt)
      #pragma unroll
      for (int nt = 0; nt < 4; ++nt)
        acc[mt][nt] = __builtin_amdgcn_mfma_f32_16x16x32_bf16(af[mt], bfr[nt], acc[mt][nt], 0, 0, 0);
  }

  // epilogue: C/D layout col = lane&15, row = quad*4 + reg
  #pragma unroll
  for (int mt = 0; mt < 4; ++mt) {
    #pragma unroll
    for (int i = 0; i < 4; ++i) {
      int grow = m_base + wm + mt * 16 + q * 4 + i;
      if (grow >= M) continue;
      #pragma unroll
      for (int nt = 0; nt < 4; ++nt) {
        int gcol = n_base + wn + nt * 16 + lm;
        if (gcol >= Nst) continue;
        float v = acc[mt][nt][i];
        if (EPI == 0) {
          v += bias[gcol];
          Cb[coff + (size_t)grow * ldc + gcol] = f2bf(v);
        } else if (EPI == 1) {
          v += bias[gcol] + res[(size_t)grow * ldr + gcol];
          Cf[(size_t)grow * ldc + gcol] = v;
        } else if (EPI == 2) {
          v += bias[gcol];
          v = 0.5f * v * (1.0f + erff(v * 0.70710678118654752f));
          Cb[coff + (size_t)grow * ldc + gcol] = f2bf(v);
        } else if (EPI == 3) {
          Cf[coff + (size_t)grow * ldc + gcol] = v * scale;
        } else {
          Cb[coff + (size_t)grow * ldc + gcol] = f2bf(v);
        }
      }
    }
  }
}

// ---------------- launch ----------------
extern "C" void kernel_launch(void* const* d_in, const int* in_sizes, int n_in,
                              void* d_out, int out_size, void* d_ws, size_t ws_size,
                              hipStream_t stream) {
  const float* x     = (const float*)d_in[0];
  const float* ln1w  = (const float*)d_in[1];
  const float* ln1b  = (const float*)d_in[2];
  const float* qkvw  = (const float*)d_in[3];
  const float* qkvb  = (const float*)d_in[4];
  const float* projw = (const float*)d_in[5];
  const float* projb = (const float*)d_in[6];
  const float* ln2w  = (const float*)d_in[7];
  const float* ln2b  = (const float*)d_in[8];
  const float* fc1w  = (const float*)d_in[9];
  const float* fc1b  = (const float*)d_in[10];
  const float* fc2w  = (const float*)d_in[11];
  const float* fc2b  = (const float*)d_in[12];
  float* out = (float*)d_out;

  // ---- workspace layout ----
  u16* qkvwT  = (u16*)d_ws;                       // [2304][768]
  u16* projwT = qkvwT  + (size_t)H3 * D_;         // [768][768]
  u16* fc1wT  = projwT + (size_t)D_ * D_;         // [3072][768]
  u16* fc2wT  = fc1wT  + (size_t)HD * D_;         // [768][3072]
  char* chunk = (char*)(fc2wT + (size_t)D_ * HD);
  const size_t wbytes = ((size_t)H3 * D_ + (size_t)D_ * D_ + 2 * (size_t)HD * D_) * 2;
  size_t avail = ws_size - wbytes;

  // per-batch chunk bytes: ybf + qkvbf + dp + P + Vt
  const size_t per_batch =
      (size_t)T_ * D_ * 2 + (size_t)T_ * H3 * 2 + (size_t)NH * TT * 4 +
      (size_t)NH * T_ * TP * 2 + (size_t)NH * 128 * TP * 2;
  int NB = (int)(avail / per_batch);
  if (NB < 1)  NB = 1;
  if (NB > B_) NB = B_;

  u16*   ybf   = (u16*)chunk;
  u16*   qkvbf = ybf + (size_t)NB * T_ * D_;
  float* dp    = (float*)(qkvbf + (size_t)NB * T_ * H3);
  u16*   P     = (u16*)(dp + (size_t)NB * NH * TT);
  u16*   Vt    = P + (size_t)NB * NH * T_ * TP;

  // ---- weights: fp32 [K,N] -> bf16 [N,K] ----
  wconv<<<dim3(H3 / 64, D_ / 64), 256, 0, stream>>>(qkvw, qkvwT, D_, H3);
  wconv<<<dim3(D_ / 64, D_ / 64), 256, 0, stream>>>(projw, projwT, D_, D_);
  wconv<<<dim3(HD / 64, D_ / 64), 256, 0, stream>>>(fc1w, fc1wT, D_, HD);
  wconv<<<dim3(D_ / 64, HD / 64), 256, 0, stream>>>(fc2w, fc2wT, HD, D_);

  // ---- attention branch, chunked over batches ----
  for (int b0 = 0; b0 < B_; b0 += NB) {
    int nb = (B_ - b0 < NB) ? (B_ - b0) : NB;
    int rows = nb * T_;
    const float* xc = x + (size_t)b0 * T_ * D_;
    float* outc = out + (size_t)b0 * T_ * D_;

    ln_bf16<<<rows, 256, 0, stream>>>(xc, ln1w, ln1b, ybf);
    gemm_bf16<0><<<dim3(H3 / 128, (rows + 127) / 128), 256, 0, stream>>>(
        ybf, D_, qkvwT, D_, qkvb, nullptr, 0, nullptr, qkvbf, H3,
        rows, H3, H3, D_, 1.f, 0);
    vt_prep<<<dim3(10, 2, nb * NH), 256, 0, stream>>>(qkvbf, Vt);
    gemm_bf16<3><<<dim3(5, 5, nb * NH), 256, 0, stream>>>(
        qkvbf, H3, qkvbf, H3, nullptr, nullptr, 0, dp, nullptr, T_,
        T_, T_, T_, DH, 0.125f, 1);
    softmax_pad<<<dim3((T_ * TP + 255) / 256, nb), 256, 0, stream>>>(dp, P);
    gemm_bf16<4><<<dim3(1, 5, nb * NH), 256, 0, stream>>>(
        P, TP, Vt, TP, nullptr, nullptr, 0, nullptr, qkvbf, H3,
        T_, DH, 128, TP, 1.f, 2);
    gemm_bf16<1><<<dim3(D_ / 128, (rows + 127) / 128), 256, 0, stream>>>(
        qkvbf, H3, projwT, D_, projb, xc, D_, outc, nullptr, D_,
        rows, D_, D_, D_, 1.f, 0);
  }

  // ---- MLP branch, chunked over rows ----
  size_t chrows = avail / ((size_t)D_ * 2 + (size_t)HD * 2);
  int CH = (chrows > (size_t)BT) ? BT : (int)chrows;
  CH &= ~127;
  if (CH < 128) CH = 128;
  for (int r0 = 0; r0 < BT; r0 += CH) {
    int rows = (BT - r0 < CH) ? (BT - r0) : CH;
    float* oc = out + (size_t)r0 * D_;
    u16* y2  = (u16*)chunk;
    u16* hdn = y2 + (size_t)CH * D_;

    ln_bf16<<<rows, 256, 0, stream>>>(oc, ln2w, ln2b, y2);
    gemm_bf16<2><<<dim3(HD / 128, (rows + 127) / 128), 256, 0, stream>>>(
        y2, D_, fc1wT, D_, fc1b, nullptr, 0, nullptr, hdn, HD,
        rows, HD, HD, D_, 1.f, 0);
    gemm_bf16<1><<<dim3(D_ / 128, (rows + 127) / 128), 256, 0, stream>>>(
        hdn, HD, fc2wT, HD, fc2b, oc, D_, oc, nullptr, D_,
        rows, D_, D_, HD, 1.f, 0);
  }
}

// Round 4
// 1453.456 us; speedup vs baseline: 3.5743x; 1.0094x over previous
//
#include <hip/hip_runtime.h>
#include <math.h>
#include <stdint.h>

typedef unsigned short u16;
typedef __attribute__((ext_vector_type(8))) short bf8;      // 8 bf16 MFMA operand (4 VGPR)
typedef __attribute__((ext_vector_type(8))) unsigned short us8;
typedef __attribute__((ext_vector_type(4))) float f4;

#define B_  32
#define T_  577
#define D_  768
#define BT  18464
#define H3  2304
#define HD  3072
#define NH  12
#define DH  64
#define TT  332929ull        // T_*T_
#define TP  608              // T_ padded to mult of 32 (K dim of AV)
#define LNEPS 1e-6f

// async global->LDS, 16B per lane; dest = wave-uniform base + lane*16
#define GLOAD_LDS16(gp, lp)                                                \
  __builtin_amdgcn_global_load_lds(                                       \
      (const __attribute__((address_space(1))) void*)(gp),                 \
      (__attribute__((address_space(3))) void*)(unsigned)(uintptr_t)(lp),  \
      16, 0, 0)

__device__ __forceinline__ u16 f2bf(float f) {
  unsigned int u = __float_as_uint(f);
  u += 0x7fffu + ((u >> 16) & 1u);       // round-to-nearest-even
  return (u16)(u >> 16);
}

// ---------------- LayerNorm fp32 -> bf16 ----------------
__global__ __launch_bounds__(256) void ln_bf16(const float* __restrict__ x,
    const float* __restrict__ w, const float* __restrict__ b, u16* __restrict__ y) {
  int row = blockIdx.x;
  const float* xr = x + (size_t)row * D_;
  int t = threadIdx.x;
  float v0 = xr[t], v1 = xr[t + 256], v2 = xr[t + 512];
  float s  = v0 + v1 + v2;
  float ss = v0*v0 + v1*v1 + v2*v2;
  #pragma unroll
  for (int o = 32; o >= 1; o >>= 1) {
    s  += __shfl_xor(s,  o, 64);
    ss += __shfl_xor(ss, o, 64);
  }
  __shared__ float rs_[4], rss_[4];
  int wid = t >> 6;
  if ((t & 63) == 0) { rs_[wid] = s; rss_[wid] = ss; }
  __syncthreads();
  s  = rs_[0]  + rs_[1]  + rs_[2]  + rs_[3];
  ss = rss_[0] + rss_[1] + rss_[2] + rss_[3];
  float mu  = s * (1.0f / D_);
  float var = ss * (1.0f / D_) - mu * mu;
  float rstd = rsqrtf(var + LNEPS);
  u16* yr = y + (size_t)row * D_;
  yr[t]       = f2bf((v0 - mu) * rstd * w[t]       + b[t]);
  yr[t + 256] = f2bf((v1 - mu) * rstd * w[t + 256] + b[t + 256]);
  yr[t + 512] = f2bf((v2 - mu) * rstd * w[t + 512] + b[t + 512]);
}

// ---------------- weight fp32 [K,N] -> bf16 transposed [N,K] ----------------
__global__ __launch_bounds__(256) void wconv(const float* __restrict__ W,
    u16* __restrict__ Wt, int K, int N) {
  __shared__ float tile[64][68];
  int n0 = blockIdx.x * 64, k0 = blockIdx.y * 64;
  int t = threadIdx.x;
  #pragma unroll
  for (int r = 0; r < 4; ++r) {
    int flat = r * 256 + t;
    int kr = flat >> 4, g = flat & 15;
    float4 v = *(const float4*)(W + (size_t)(k0 + kr) * N + n0 + g * 4);
    *(float4*)&tile[kr][g * 4] = v;
  }
  __syncthreads();
  #pragma unroll
  for (int r = 0; r < 2; ++r) {
    int flat = r * 256 + t;
    int n = flat >> 3, g2 = flat & 7;
    us8 o;
    #pragma unroll
    for (int j = 0; j < 8; ++j) o[j] = f2bf(tile[g2 * 8 + j][n]);
    *(us8*)(Wt + (size_t)(n0 + n) * K + k0 + g2 * 8) = o;
  }
}

// ---------------- build Vt [z][128][TP] from qkvbf V-slot ----------------
__global__ __launch_bounds__(256) void vt_prep(const u16* __restrict__ qkvbf,
    u16* __restrict__ Vt) {
  int z = blockIdx.z;
  int bb = z / NH, h = z - bb * NH;
  u16* out = Vt + (size_t)z * 128 * TP;
  int k0 = blockIdx.x * 64;
  int t = threadIdx.x;
  if (blockIdx.y == 1) {
    #pragma unroll
    for (int r = 0; r < 2; ++r) {
      int flat = r * 256 + t;
      int n = 64 + (flat >> 3), g = flat & 7;
      int kc = k0 + g * 8;
      if (kc < TP) {
        us8 zz = {0,0,0,0,0,0,0,0};
        *(us8*)(out + (size_t)n * TP + kc) = zz;
      }
    }
    return;
  }
  __shared__ u16 tile[64][72];
  const u16* src = qkvbf + ((size_t)bb * T_) * H3 + 2 * D_ + h * DH;
  #pragma unroll
  for (int r = 0; r < 2; ++r) {
    int flat = r * 256 + t;
    int kr = flat >> 3, g = flat & 7;
    int gk = k0 + kr;
    us8 v = {0,0,0,0,0,0,0,0};
    if (gk < T_) v = *(const us8*)(src + (size_t)gk * H3 + g * 8);
    *(us8*)&tile[kr][g * 8] = v;
  }
  __syncthreads();
  #pragma unroll
  for (int r = 0; r < 2; ++r) {
    int flat = r * 256 + t;
    int n = flat >> 3, g2 = flat & 7;
    int kc = k0 + g2 * 8;
    if (kc < TP) {
      us8 o;
      #pragma unroll
      for (int j = 0; j < 8; ++j) o[j] = tile[g2 * 8 + j][n];
      *(us8*)(out + (size_t)n * TP + kc) = o;
    }
  }
}

// ---------------- softmax over heads; fp32 dp -> bf16 P (padded to TP) ----------------
__global__ __launch_bounds__(256) void softmax_pad(const float* __restrict__ dp,
    u16* __restrict__ P) {
  int bb = blockIdx.y;
  int i = blockIdx.x * 256 + threadIdx.x;
  if (i >= T_ * TP) return;
  int qq = i / TP, kp = i - qq * TP;
  u16* Pb = P + (size_t)bb * NH * T_ * TP + (size_t)qq * TP + kp;
  if (kp >= T_) {
    #pragma unroll
    for (int h = 0; h < NH; ++h) Pb[(size_t)h * T_ * TP] = 0;
    return;
  }
  const float* db = dp + (size_t)bb * NH * TT + (size_t)qq * T_ + kp;
  float v[NH];
  float m = -1e30f;
  #pragma unroll
  for (int h = 0; h < NH; ++h) { v[h] = db[(size_t)h * TT]; m = fmaxf(m, v[h]); }
  float s = 0.f;
  #pragma unroll
  for (int h = 0; h < NH; ++h) { v[h] = expf(v[h] - m); s += v[h]; }
  float inv = 1.0f / s;
  #pragma unroll
  for (int h = 0; h < NH; ++h) Pb[(size_t)h * T_ * TP] = f2bf(v[h] * inv);
}

// ---------------- bf16 MFMA GEMM: C = epi(A[M,K] @ Bt[N,K]^T) ----------------
// 128x128 tile, BK=32, 16x16x32 MFMA, 4 waves each 64x64, global_load_lds staging.
// EPI: 0 = bias -> bf16 C        1 = bias+res -> f32 C
//      2 = bias+gelu -> bf16 C   3 = *scale -> f32 C      4 = plain -> bf16 C
template <int EPI>
__global__ __launch_bounds__(256) void gemm_bf16(
    const u16* __restrict__ Abase, int lda,
    const u16* __restrict__ Bbase, int ldb,
    const float* __restrict__ bias,
    const float* __restrict__ res, int ldr,
    float* __restrict__ Cf, u16* __restrict__ Cb, int ldc,
    int M, int Nst, int Nb, int K, float scale, int bmode) {
  __shared__ u16 As[128 * 32];
  __shared__ u16 Bs[128 * 32];
  int z = blockIdx.z;
  size_t aoff = 0, boff = 0, coff = 0;
  if (bmode == 1) {
    int bb = z / NH, h = z - bb * NH;
    aoff = (size_t)bb * T_ * H3 + (size_t)h * DH;
    boff = aoff + D_;
    coff = (size_t)z * TT;
  } else if (bmode == 2) {
    int bb = z / NH, h = z - bb * NH;
    aoff = (size_t)z * T_ * TP;
    boff = (size_t)z * 128 * TP;
    coff = (size_t)bb * T_ * H3 + (size_t)h * DH;
  }
  const u16* A  = Abase + aoff;
  const u16* Bt = Bbase + boff;

  // XCD-aware swizzle: give each XCD a contiguous flat-id range so the
  // N-blocks sharing one A row-tile run back-to-back on one XCD's L2.
  int bx = blockIdx.x, by = blockIdx.y;
  if (bmode == 0) {
    int gx = gridDim.x;
    int g  = gx * gridDim.y;
    int i  = by * gx + bx;
    int chunk = g >> 3, rem = g & 7;
    int xcd = i & 7, loc = i >> 3;
    int start = xcd * chunk + (xcd < rem ? xcd : rem);
    int o = start + loc;
    by = o / gx; bx = o - by * gx;
  }
  int m_base = by * 128, n_base = bx * 128;

  int tid = threadIdx.x;
  int wid = tid >> 6, lane = tid & 63;
  int wm = (wid >> 1) * 64, wn = (wid & 1) * 64;
  int lm = lane & 15, q = lane >> 4;
  int srow = tid >> 2, sg = tid & 3;

  int gm0 = m_base + srow;       gm0 = gm0 < M ? gm0 : M - 1;
  int gm1 = m_base + 64 + srow;  gm1 = gm1 < M ? gm1 : M - 1;
  int gn0 = n_base + srow;       gn0 = gn0 < Nb ? gn0 : Nb - 1;
  int gn1 = n_base + 64 + srow;  gn1 = gn1 < Nb ? gn1 : Nb - 1;
  const u16* a0 = A  + (size_t)gm0 * lda + sg * 8;
  const u16* a1 = A  + (size_t)gm1 * lda + sg * 8;
  const u16* b0 = Bt + (size_t)gn0 * ldb + sg * 8;
  const u16* b1 = Bt + (size_t)gn1 * ldb + sg * 8;
  u16* lA = As + wid * 512;   // wave-uniform base; lane dest = +lane*16B
  u16* lB = Bs + wid * 512;

  f4 acc[4][4] = {};

  for (int kc = 0; kc < K; kc += 32) {
    GLOAD_LDS16(a0 + kc, lA);
    GLOAD_LDS16(a1 + kc, lA + 2048);
    GLOAD_LDS16(b0 + kc, lB);
    GLOAD_LDS16(b1 + kc, lB + 2048);
    __syncthreads();
    bf8 af[4], bfr[4];
    #pragma unroll
    for (int mt = 0; mt < 4; ++mt)
      af[mt] = *(const bf8*)&As[(wm + mt * 16 + lm) * 32 + q * 8];
    #pragma unroll
    for (int nt = 0; nt < 4; ++nt)
      bfr[nt] = *(const bf8*)&Bs[(wn + nt * 16 + lm) * 32 + q * 8];
    #pragma unroll
    for (int mt = 0; mt < 4; ++mt)
      #pragma unroll
      for (int nt = 0; nt < 4; ++nt)
        acc[mt][nt] = __builtin_amdgcn_mfma_f32_16x16x32_bf16(af[mt], bfr[nt], acc[mt][nt], 0, 0, 0);
    __syncthreads();
  }

  // epilogue: C/D layout col = lane&15, row = quad*4 + reg
  #pragma unroll
  for (int mt = 0; mt < 4; ++mt) {
    #pragma unroll
    for (int i = 0; i < 4; ++i) {
      int grow = m_base + wm + mt * 16 + q * 4 + i;
      if (grow >= M) continue;
      #pragma unroll
      for (int nt = 0; nt < 4; ++nt) {
        int gcol = n_base + wn + nt * 16 + lm;
        if (gcol >= Nst) continue;
        float v = acc[mt][nt][i];
        if (EPI == 0) {
          v += bias[gcol];
          Cb[coff + (size_t)grow * ldc + gcol] = f2bf(v);
        } else if (EPI == 1) {
          v += bias[gcol] + res[(size_t)grow * ldr + gcol];
          Cf[(size_t)grow * ldc + gcol] = v;
        } else if (EPI == 2) {
          v += bias[gcol];
          v = 0.5f * v * (1.0f + erff(v * 0.70710678118654752f));
          Cb[coff + (size_t)grow * ldc + gcol] = f2bf(v);
        } else if (EPI == 3) {
          Cf[coff + (size_t)grow * ldc + gcol] = v * scale;
        } else {
          Cb[coff + (size_t)grow * ldc + gcol] = f2bf(v);
        }
      }
    }
  }
}

// ---------------- launch ----------------
extern "C" void kernel_launch(void* const* d_in, const int* in_sizes, int n_in,
                              void* d_out, int out_size, void* d_ws, size_t ws_size,
                              hipStream_t stream) {
  const float* x     = (const float*)d_in[0];
  const float* ln1w  = (const float*)d_in[1];
  const float* ln1b  = (const float*)d_in[2];
  const float* qkvw  = (const float*)d_in[3];
  const float* qkvb  = (const float*)d_in[4];
  const float* projw = (const float*)d_in[5];
  const float* projb = (const float*)d_in[6];
  const float* ln2w  = (const float*)d_in[7];
  const float* ln2b  = (const float*)d_in[8];
  const float* fc1w  = (const float*)d_in[9];
  const float* fc1b  = (const float*)d_in[10];
  const float* fc2w  = (const float*)d_in[11];
  const float* fc2b  = (const float*)d_in[12];
  float* out = (float*)d_out;

  // ---- workspace layout ----
  u16* qkvwT  = (u16*)d_ws;                       // [2304][768]
  u16* projwT = qkvwT  + (size_t)H3 * D_;         // [768][768]
  u16* fc1wT  = projwT + (size_t)D_ * D_;         // [3072][768]
  u16* fc2wT  = fc1wT  + (size_t)HD * D_;         // [768][3072]
  char* chunk = (char*)(fc2wT + (size_t)D_ * HD);
  const size_t wbytes = ((size_t)H3 * D_ + (size_t)D_ * D_ + 2 * (size_t)HD * D_) * 2;
  size_t avail = ws_size - wbytes;

  const size_t per_batch =
      (size_t)T_ * D_ * 2 + (size_t)T_ * H3 * 2 + (size_t)NH * TT * 4 +
      (size_t)NH * T_ * TP * 2 + (size_t)NH * 128 * TP * 2;
  int NB = (int)(avail / per_batch);
  if (NB < 1)  NB = 1;
  if (NB > B_) NB = B_;

  u16*   ybf   = (u16*)chunk;
  u16*   qkvbf = ybf + (size_t)NB * T_ * D_;
  float* dp    = (float*)(qkvbf + (size_t)NB * T_ * H3);
  u16*   P     = (u16*)(dp + (size_t)NB * NH * TT);
  u16*   Vt    = P + (size_t)NB * NH * T_ * TP;

  // ---- weights: fp32 [K,N] -> bf16 [N,K] ----
  wconv<<<dim3(H3 / 64, D_ / 64), 256, 0, stream>>>(qkvw, qkvwT, D_, H3);
  wconv<<<dim3(D_ / 64, D_ / 64), 256, 0, stream>>>(projw, projwT, D_, D_);
  wconv<<<dim3(HD / 64, D_ / 64), 256, 0, stream>>>(fc1w, fc1wT, D_, HD);
  wconv<<<dim3(D_ / 64, HD / 64), 256, 0, stream>>>(fc2w, fc2wT, HD, D_);

  // ---- attention branch, chunked over batches ----
  for (int b0 = 0; b0 < B_; b0 += NB) {
    int nb = (B_ - b0 < NB) ? (B_ - b0) : NB;
    int rows = nb * T_;
    const float* xc = x + (size_t)b0 * T_ * D_;
    float* outc = out + (size_t)b0 * T_ * D_;

    ln_bf16<<<rows, 256, 0, stream>>>(xc, ln1w, ln1b, ybf);
    gemm_bf16<0><<<dim3(H3 / 128, (rows + 127) / 128), 256, 0, stream>>>(
        ybf, D_, qkvwT, D_, qkvb, nullptr, 0, nullptr, qkvbf, H3,
        rows, H3, H3, D_, 1.f, 0);
    vt_prep<<<dim3(10, 2, nb * NH), 256, 0, stream>>>(qkvbf, Vt);
    gemm_bf16<3><<<dim3(5, 5, nb * NH), 256, 0, stream>>>(
        qkvbf, H3, qkvbf, H3, nullptr, nullptr, 0, dp, nullptr, T_,
        T_, T_, T_, DH, 0.125f, 1);
    softmax_pad<<<dim3((T_ * TP + 255) / 256, nb), 256, 0, stream>>>(dp, P);
    gemm_bf16<4><<<dim3(1, 5, nb * NH), 256, 0, stream>>>(
        P, TP, Vt, TP, nullptr, nullptr, 0, nullptr, qkvbf, H3,
        T_, DH, 128, TP, 1.f, 2);
    gemm_bf16<1><<<dim3(D_ / 128, (rows + 127) / 128), 256, 0, stream>>>(
        qkvbf, H3, projwT, D_, projb, xc, D_, outc, nullptr, D_,
        rows, D_, D_, D_, 1.f, 0);
  }

  // ---- MLP branch, chunked over rows ----
  size_t chrows = avail / ((size_t)D_ * 2 + (size_t)HD * 2);
  int CH = (chrows > (size_t)BT) ? BT : (int)chrows;
  CH &= ~127;
  if (CH < 128) CH = 128;
  for (int r0 = 0; r0 < BT; r0 += CH) {
    int rows = (BT - r0 < CH) ? (BT - r0) : CH;
    float* oc = out + (size_t)r0 * D_;
    u16* y2  = (u16*)chunk;
    u16* hdn = y2 + (size_t)CH * D_;

    ln_bf16<<<rows, 256, 0, stream>>>(oc, ln2w, ln2b, y2);
    gemm_bf16<2><<<dim3(HD / 128, (rows + 127) / 128), 256, 0, stream>>>(
        y2, D_, fc1wT, D_, fc1b, nullptr, 0, nullptr, hdn, HD,
        rows, HD, HD, D_, 1.f, 0);
    gemm_bf16<1><<<dim3(D_ / 128, (rows + 127) / 128), 256, 0, stream>>>(
        hdn, HD, fc2wT, HD, fc2b, oc, D_, oc, nullptr, D_,
        rows, D_, D_, HD, 1.f, 0);
  }
}